// Round 20
// baseline (153.815 us; speedup 1.0000x reference)
//
#include <hip/hip_runtime.h>
#include <hip/hip_bf16.h>

#define LDIM 8192
#define HDIM 16
#define DDIM 64
#define NHEADPAIR 64          // N*H
#define ROWSTRIDE 1024        // H*D floats between consecutive l for fixed h
#define KVSZ 4160             // 64*64 KV + 64 ksum
#define EPSF 1e-6f
#define CHUNKS 128            // l-chunks per (n,h)
#define RPB 64                // rows per block = LDIM/CHUNKS
#define LROW 36               // padded transposed row in uints (32 slots + 4 pad)

typedef float f32x4 __attribute__((ext_vector_type(4)));
typedef short s16x8 __attribute__((ext_vector_type(8)));   // 8 bf16 (4 VGPRs)

__device__ __forceinline__ float featmap(float x) {
    // elu(x)+1 : x>0 -> x+1 ; x<=0 -> exp(x)
    return x > 0.0f ? x + 1.0f : __expf(x);
}

__device__ __forceinline__ unsigned int pack_bf16x2(float a, float b) {
    union { __hip_bfloat162 h; unsigned int u; } x;
    x.h = __float22bfloat162_rn(make_float2(a, b));   // elem0 -> low 16 bits
    return x.u;
}

__device__ __forceinline__ unsigned short bf16_of(float a) {
    union { __hip_bfloat16 h; unsigned short u; } cv;
    cv.h = __float2bfloat16(a);
    return cv.u;
}

// validated swizzle: XOR slot bits 2-3 with d bits 3-4 (16B-align-preserving)
__device__ __forceinline__ int swz(int d) { return ((d >> 3) & 3) << 2; }

// async global->LDS, 16B per lane, LDS dest = uniform base + lane*16; global src per-lane
__device__ __forceinline__ void gload_lds16(const float* g, float* l) {
    __builtin_amdgcn_global_load_lds(
        (const __attribute__((address_space(1))) void*)g,
        (__attribute__((address_space(3))) void*)l, 16, 0, 0);
}

// ---------------- Phase 1 (one-shot, ASYNC gload_lds staging) -----------------------
// R15/R16 one-shot kernel with the staging mechanism replaced: global_load_lds pulls
// the block's whole 32KB K/V tile into a LINEAR fp32 LDS buffer with ZERO VGPR cost,
// so the compiler cannot sink the loads (the failure that capped every prior variant
// at ~4 loads in flight / VGPR_Count 52-64). All 32 instructions are in flight at
// once: ~96KB/CU outstanding at 3 blocks/CU >> the ~22KB Little's-law requirement.
// Then: barrier -> LDS->LDS transform (featmap, pack bf16, validated transposed
// swizzled layout) -> barrier -> unchanged MFMA/epilogue.
__global__ __launch_bounds__(256) void kv_oneshot_kernel(
    const float* __restrict__ Kp, const float* __restrict__ Vp,
    unsigned short* __restrict__ part)
{
    __shared__ float RAW[2 * RPB * 64];      // [K|V][row][64] linear fp32
    __shared__ unsigned int KT[64 * LROW];   // [d][slot ^ swz(d)] bf16x2
    __shared__ unsigned int VT[64 * LROW];   // [m][slot ^ swz(m)]

    const int nh   = blockIdx.x;
    const int ch   = blockIdx.y;
    const int n    = nh >> 4;
    const int h    = nh & 15;
    const int t    = threadIdx.x;
    const int wave = t >> 6;
    const int lane = t & 63;

    // ---- async stage: waves 0-1 -> K rows 0-31/32-63; waves 2-3 -> V ----
    {
        const float* Sp = (wave < 2) ? Kp : Vp;
        float* rb = RAW + (wave >> 1) * (RPB * 64);
        const int w01 = wave & 1;
        const size_t gbase = ((size_t)n * LDIM + (size_t)ch * RPB) * ROWSTRIDE
                           + h * DDIM;
        const int rl = lane >> 4;            // row within quad
        const int c4 = (lane & 15) * 4;      // float offset of 16B granule
#pragma unroll
        for (int i = 0; i < 8; ++i) {
            const int r0 = w01 * 32 + i * 4; // uniform per wave
            gload_lds16(Sp + gbase + (size_t)(r0 + rl) * ROWSTRIDE + c4,
                        rb + r0 * 64);
        }
    }
    __syncthreads();                          // drains all async stages

    // ---- LDS->LDS transform (R16's validated map, src = RAW) ----
    {
        const bool isK   = (t < 128);
        const int  uw    = (t >> 6) & 1;
        const int  col16 = lane & 15;
        const int  rv    = lane >> 4;
        const float* raw = RAW + (isK ? 0 : RPB * 64);
        unsigned int* T  = isK ? KT : VT;
#pragma unroll
        for (int g = 0; g < 4; ++g) {
            const int gg = uw * 4 + g;       // 8-row group 0..7
            const int r1 = gg * 8 + rv;      // rows rv, rv+4 of the group
            const int r2 = r1 + 4;
            float4 L1 = *(const float4*)&raw[r1 * 64 + col16 * 4];
            float4 L2 = *(const float4*)&raw[r2 * 64 + col16 * 4];
            float a[4] = { L1.x, L1.y, L1.z, L1.w };
            float b[4] = { L2.x, L2.y, L2.z, L2.w };
            if (isK) {
#pragma unroll
                for (int j = 0; j < 4; ++j) { a[j] = featmap(a[j]); b[j] = featmap(b[j]); }
            }
            const int slot = gg * 4 + rv;    // 0..31
#pragma unroll
            for (int j = 0; j < 4; ++j) {
                const int d = col16 * 4 + j;
                T[d * LROW + (slot ^ swz(d))] = pack_bf16x2(a[j], b[j]);
            }
        }
    }
    __syncthreads();

    // ---- compute: wave = 16-d band; 2 k-steps x (1 ksum + 4 m-tile) MFMAs ----
    const int fr = lane & 15;
    const int fk = lane >> 4;
    const int d0 = wave * 16;

    f32x4 acc[4];
    f32x4 zac = (f32x4){0.f, 0.f, 0.f, 0.f};
#pragma unroll
    for (int mb = 0; mb < 4; ++mb) acc[mb] = (f32x4){0.f, 0.f, 0.f, 0.f};
    s16x8 ones;
#pragma unroll
    for (int i = 0; i < 8; ++i) ones[i] = (short)0x3F80;   // bf16 1.0

    const int dA = d0 + fr;
#pragma unroll
    for (int kk = 0; kk < 2; ++kk) {
        const int slot = kk * 16 + fk * 4;
        s16x8 A = *(const s16x8*)&KT[dA * LROW + (slot ^ swz(dA))];
        zac = __builtin_amdgcn_mfma_f32_16x16x32_bf16(A, ones, zac, 0, 0, 0);
#pragma unroll
        for (int mb = 0; mb < 4; ++mb) {
            const int m = mb * 16 + fr;
            s16x8 B = *(const s16x8*)&VT[m * LROW + (slot ^ swz(m))];
            acc[mb] = __builtin_amdgcn_mfma_f32_16x16x32_bf16(A, B, acc[mb], 0, 0, 0);
        }
    }

    // ---- epilogue: bf16 partial. D row = d (fk*4+reg), D col = m (fr) ----
    unsigned short* p = part + ((size_t)nh * CHUNKS + ch) * KVSZ;
#pragma unroll
    for (int mb = 0; mb < 4; ++mb)
#pragma unroll
        for (int reg = 0; reg < 4; ++reg)
            p[(d0 + fk * 4 + reg) * 64 + mb * 16 + fr] = bf16_of(acc[mb][reg]);
    if (fr == 0)
#pragma unroll
        for (int reg = 0; reg < 4; ++reg)
            p[4096 + d0 + fk * 4 + reg] = bf16_of(zac[reg]);
}

// ---------------- Phase 1b: reduce bf16 partials, emit bf16 KV + ksum ---------------
__global__ __launch_bounds__(256) void kv_reduce_kernel(
    const unsigned short* __restrict__ part, unsigned short* __restrict__ kvh)
{
    const int nh = blockIdx.y;
    const int e  = blockIdx.x * 256 + threadIdx.x;
    if (e >= KVSZ) return;
    float s = 0.0f;
    for (int c = 0; c < CHUNKS; ++c) {
        union { unsigned short u; __hip_bfloat16 h; } cv;
        cv.u = part[((size_t)nh * CHUNKS + c) * KVSZ + e];
        s += __bfloat162float(cv.h);
    }
    kvh[(size_t)nh * KVSZ + e] = bf16_of(s);
}

// ---------------- Phase 2 (MFMA): out[l][m] = Z * sum_d fmQ[l][d] * KV[m][d] --------
// Unchanged (validated).
__global__ __launch_bounds__(256) void attn_mfma_kernel(
    const float* __restrict__ Qp, const unsigned short* __restrict__ kvh,
    float* __restrict__ out)
{
    __shared__ unsigned int kvU[64][36];
    __shared__ unsigned int ksU[36];
    __shared__ unsigned int qU[128][36];

    const int nh = blockIdx.y;
    const int n  = nh >> 4;
    const int h  = nh & 15;
    const int t  = threadIdx.x;

    {
        const unsigned int* kvg = (const unsigned int*)(kvh + (size_t)nh * KVSZ);
        const int r  = t >> 2;
        const int c0 = (t & 3) * 8;
        uint4 x = *(const uint4*)(kvg + r * 32 + c0);
        uint4 y = *(const uint4*)(kvg + r * 32 + c0 + 4);
        *(uint4*)&kvU[r][c0]     = x;
        *(uint4*)&kvU[r][c0 + 4] = y;
        if (t < 32) ksU[t] = kvg[2048 + t];
    }

    {
        const int qr = t >> 1;
        const float* qg = Qp + ((((size_t)n * LDIM) + (size_t)blockIdx.x * 128 + qr)
                                * HDIM + h) * DDIM + (t & 1) * 32;
        unsigned int q[16];
#pragma unroll
        for (int j = 0; j < 8; ++j) {
            float4 f = *(const float4*)(qg + j * 4);
            q[2 * j]     = pack_bf16x2(featmap(f.x), featmap(f.y));
            q[2 * j + 1] = pack_bf16x2(featmap(f.z), featmap(f.w));
        }
        uint4* dst = (uint4*)&qU[qr][(t & 1) * 16];
        dst[0] = make_uint4(q[0],  q[1],  q[2],  q[3]);
        dst[1] = make_uint4(q[4],  q[5],  q[6],  q[7]);
        dst[2] = make_uint4(q[8],  q[9],  q[10], q[11]);
        dst[3] = make_uint4(q[12], q[13], q[14], q[15]);
    }
    __syncthreads();

    const int wave = t >> 6;
    const int lane = t & 63;
    const int fr = lane & 15;
    const int fk = lane >> 4;

    s16x8 bF[4][2], kF[2];
#pragma unroll
    for (int mt = 0; mt < 4; ++mt)
#pragma unroll
        for (int kk = 0; kk < 2; ++kk)
            bF[mt][kk] = *(const s16x8*)&kvU[mt * 16 + fr][kk * 16 + fk * 4];
#pragma unroll
    for (int kk = 0; kk < 2; ++kk)
        kF[kk] = *(const s16x8*)&ksU[kk * 16 + fk * 4];

    f32x4 acc[2][4];
    f32x4 zac[2];
#pragma unroll
    for (int lt = 0; lt < 2; ++lt) {
        zac[lt] = (f32x4){0.f, 0.f, 0.f, 0.f};
#pragma unroll
        for (int mt = 0; mt < 4; ++mt) acc[lt][mt] = (f32x4){0.f, 0.f, 0.f, 0.f};
    }

#pragma unroll
    for (int kk = 0; kk < 2; ++kk) {
#pragma unroll
        for (int lt = 0; lt < 2; ++lt) {
            s16x8 A = *(const s16x8*)&qU[wave * 32 + lt * 16 + fr][kk * 16 + fk * 4];
            zac[lt] = __builtin_amdgcn_mfma_f32_16x16x32_bf16(A, kF[kk], zac[lt], 0, 0, 0);
#pragma unroll
            for (int mt = 0; mt < 4; ++mt)
                acc[lt][mt] = __builtin_amdgcn_mfma_f32_16x16x32_bf16(
                    A, bF[mt][kk], acc[lt][mt], 0, 0, 0);
        }
    }

#pragma unroll
    for (int lt = 0; lt < 2; ++lt) {
#pragma unroll
        for (int reg = 0; reg < 4; ++reg) {
            const int row = blockIdx.x * 128 + wave * 32 + lt * 16 + fk * 4 + reg;
            const float z = 1.0f / (zac[lt][reg] + EPSF);
            float* orow = out + (((size_t)n * LDIM + row) * HDIM + h) * DDIM;
#pragma unroll
            for (int mt = 0; mt < 4; ++mt)
                orow[mt * 16 + fr] = acc[lt][mt][reg] * z;
        }
    }
}

extern "C" void kernel_launch(void* const* d_in, const int* in_sizes, int n_in,
                              void* d_out, int out_size, void* d_ws, size_t ws_size,
                              hipStream_t stream) {
    const float* Q = (const float*)d_in[0];
    const float* K = (const float*)d_in[1];
    const float* V = (const float*)d_in[2];
    float* out = (float*)d_out;

    unsigned short* part = (unsigned short*)d_ws;   // 64*128*4160*2 = 68.2 MB
    unsigned short* kvh  = part + (size_t)NHEADPAIR * CHUNKS * KVSZ;

    dim3 g1(NHEADPAIR, CHUNKS);
    kv_oneshot_kernel<<<g1, 256, 0, stream>>>(K, V, part);
    dim3 gr((KVSZ + 255) / 256, NHEADPAIR);
    kv_reduce_kernel<<<gr, 256, 0, stream>>>(part, kvh);
    dim3 g2(LDIM / 128, NHEADPAIR);
    attn_mfma_kernel<<<g2, 256, 0, stream>>>(Q, kvh, out);
}